// Round 6
// baseline (3789.068 us; speedup 1.0000x reference)
//
#include <hip/hip_runtime.h>
#include <hip/hip_bf16.h>

#define BB 8
#define NN 2048
#define CC 256
#define DKK 64
#define DVV 256
#define COFF 60.0f

typedef __attribute__((ext_vector_type(8))) short bf16x8;
typedef __attribute__((ext_vector_type(4))) float f32x4;

#define MFMA16 __builtin_amdgcn_mfma_f32_16x16x32_bf16

static __device__ __forceinline__ unsigned short f2bf(float f) {
    unsigned int u = __float_as_uint(f);
    u += 0x7fffu + ((u >> 16) & 1u);
    return (unsigned short)(u >> 16);
}
static __device__ __forceinline__ float bf2f(unsigned short h) {
    return __uint_as_float(((unsigned int)h) << 16);
}

// ---------------- kernel 0: split W into bf16 h/l, rows: q(0..63)|k|v -----
__global__ void k_wt(const float* __restrict__ Wq, const float* __restrict__ Wk,
                     const float* __restrict__ Wv,
                     unsigned short* __restrict__ Wh, unsigned short* __restrict__ Wl) {
    int idx = blockIdx.x * 256 + threadIdx.x;
    if (idx >= 384 * 256) return;
    int d = idx >> 8, c = idx & 255;
    float w;
    if (d < 64)       w = Wq[d * 256 + c];
    else if (d < 128) w = Wk[(d - 64) * 256 + c];
    else              w = Wv[(d - 128) * 256 + c];
    unsigned short h = f2bf(w);
    Wh[idx] = h;
    Wl[idx] = f2bf(w - bf2f(h));
}

// ---------------- kernel 0b: split x into bf16 h/l ------------------------
__global__ __launch_bounds__(256) void k_split(
    const float* __restrict__ x,
    unsigned short* __restrict__ xh, unsigned short* __restrict__ xl) {
    int tid = blockIdx.x * 256 + threadIdx.x;
    const float4* xp = (const float4*)x + tid * 2;
    float4 a = xp[0], b = xp[1];
    float v[8] = {a.x, a.y, a.z, a.w, b.x, b.y, b.z, b.w};
    ushort4 h4[2], l4[2];
    #pragma unroll
    for (int i = 0; i < 8; ++i) {
        unsigned short h = f2bf(v[i]);
        ((unsigned short*)h4)[i] = h;
        ((unsigned short*)l4)[i] = f2bf(v[i] - bf2f(h));
    }
    ((ushort4*)xh)[tid * 2]     = h4[0];
    ((ushort4*)xh)[tid * 2 + 1] = h4[1];
    ((ushort4*)xl)[tid * 2]     = l4[0];
    ((ushort4*)xl)[tid * 2 + 1] = l4[1];
}

// ---------------- kernel 1a: v projection -> vt[b][mt][d][64] -------------
__global__ __launch_bounds__(256) void k_vproj(
    const unsigned short* __restrict__ xh, const unsigned short* __restrict__ Wh,
    unsigned short* __restrict__ vt)
{
    int w = threadIdx.x >> 6, lane = threadIdx.x & 63;
    int t = lane & 15, qd = lane >> 4;
    int n0 = blockIdx.x * 16;
    int bn = n0 + t;
    bf16x8 bfr[8];
    const unsigned short* bp = xh + (size_t)bn * 256 + qd * 8;
    #pragma unroll
    for (int c = 0; c < 8; ++c) bfr[c] = *(const bf16x8*)(bp + c * 32);
    int b = bn >> 11, n = bn & 2047;
    int mt = n >> 6, mo = n & 63;
    #pragma unroll
    for (int k = 0; k < 4; ++k) {
        int dt = 8 + w * 4 + k;
        const unsigned short* ap = Wh + (size_t)(dt * 16 + t) * 256 + qd * 8;
        f32x4 acc = {0.f, 0.f, 0.f, 0.f};
        #pragma unroll
        for (int c = 0; c < 8; ++c) {
            bf16x8 a = *(const bf16x8*)(ap + c * 32);
            acc = MFMA16(a, bfr[c], acc, 0, 0, 0);
        }
        #pragma unroll
        for (int r = 0; r < 4; ++r) {
            int dvd = dt * 16 + qd * 4 + r - 128;
            vt[(((size_t)b * 32 + mt) * 256 + dvd) * 64 + mo] = f2bf(acc[r]);
        }
    }
}

// ---------------- kernel 1b: q/k projection (3-pass split-bf16 MFMA) ------
__global__ __launch_bounds__(256) void k_qkproj(
    const unsigned short* __restrict__ xh, const unsigned short* __restrict__ xl,
    const unsigned short* __restrict__ Wh, const unsigned short* __restrict__ Wl,
    unsigned short* __restrict__ qh, unsigned short* __restrict__ ql,
    unsigned short* __restrict__ kh, unsigned short* __restrict__ kl)
{
    int w = threadIdx.x >> 6, lane = threadIdx.x & 63;
    int t = lane & 15, qd = lane >> 4;
    int n0 = blockIdx.x * 16;
    int bn = n0 + t;
    bf16x8 bh[8], bl[8];
    const unsigned short* bph = xh + (size_t)bn * 256 + qd * 8;
    const unsigned short* bpl = xl + (size_t)bn * 256 + qd * 8;
    #pragma unroll
    for (int c = 0; c < 8; ++c) {
        bh[c] = *(const bf16x8*)(bph + c * 32);
        bl[c] = *(const bf16x8*)(bpl + c * 32);
    }
    #pragma unroll
    for (int k = 0; k < 2; ++k) {
        int dt = w * 2 + k;
        const unsigned short* aph = Wh + (size_t)(dt * 16 + t) * 256 + qd * 8;
        const unsigned short* apl = Wl + (size_t)(dt * 16 + t) * 256 + qd * 8;
        f32x4 acc = {0.f, 0.f, 0.f, 0.f};
        #pragma unroll
        for (int c = 0; c < 8; ++c) {
            bf16x8 a = *(const bf16x8*)(aph + c * 32);
            bf16x8 al = *(const bf16x8*)(apl + c * 32);
            acc = MFMA16(a, bh[c], acc, 0, 0, 0);
            acc = MFMA16(a, bl[c], acc, 0, 0, 0);
            acc = MFMA16(al, bh[c], acc, 0, 0, 0);
        }
        ushort4 h4, l4;
        #pragma unroll
        for (int r = 0; r < 4; ++r) {
            unsigned short h = f2bf(acc[r]);
            ((unsigned short*)&h4)[r] = h;
            ((unsigned short*)&l4)[r] = f2bf(acc[r] - bf2f(h));
        }
        int dbase = dt * 16 + qd * 4;
        if (dbase < 64) {
            *(ushort4*)(qh + (size_t)bn * 64 + dbase) = h4;
            *(ushort4*)(ql + (size_t)bn * 64 + dbase) = l4;
        } else {
            *(ushort4*)(kh + (size_t)bn * 64 + dbase - 64) = h4;
            *(ushort4*)(kl + (size_t)bn * 64 + dbase - 64) = l4;
        }
    }
}

// ---------------- kernel 2: QK -> E[b][mt][n][64], rcs, scale vt ----------
// grid (32 mt, 8 b), 1024 thr = 16 waves. wave (i = m-16sub 0..3, j = n-quarter).
// Register double-buffered q-frag loads; barrier-free main loop.
__global__ __launch_bounds__(1024, 4) void k_qk(
    const unsigned short* __restrict__ qh, const unsigned short* __restrict__ ql,
    const unsigned short* __restrict__ kh, const unsigned short* __restrict__ kl,
    unsigned short* __restrict__ E, unsigned short* __restrict__ rcsb,
    unsigned short* __restrict__ vt)
{
    __shared__ float csbuf[4][64];
    __shared__ float rcs_s[64];
    int tid = threadIdx.x;
    int w = tid >> 6, lane = tid & 63;
    int t = lane & 15, qd = lane >> 4;
    int b = blockIdx.y, mt = blockIdx.x, m0 = mt * 64;
    int i = w >> 2, j = w & 3;

    // persistent A-frags: k rows m0 + 16i + t
    const unsigned short* aph = kh + ((size_t)b * 2048 + m0 + 16 * i + t) * 64 + qd * 8;
    const unsigned short* apl = kl + ((size_t)b * 2048 + m0 + 16 * i + t) * 64 + qd * 8;
    bf16x8 ah0 = *(const bf16x8*)aph;
    bf16x8 ah1 = *(const bf16x8*)(aph + 32);
    bf16x8 al0 = *(const bf16x8*)apl;
    bf16x8 al1 = *(const bf16x8*)(apl + 32);

    unsigned short* Eb = E + ((size_t)b * 32 + mt) * (2048 * 64);
    const unsigned short* qbh = qh + ((size_t)b * 2048 + j * 512 + t) * 64 + qd * 8;
    const unsigned short* qbl = ql + ((size_t)b * 2048 + j * 512 + t) * 64 + qd * 8;

    bf16x8 nb[2][4];
    nb[0][0] = *(const bf16x8*)qbh;
    nb[0][1] = *(const bf16x8*)(qbh + 32);
    nb[0][2] = *(const bf16x8*)qbl;
    nb[0][3] = *(const bf16x8*)(qbl + 32);

    float ssum[4] = {0.f, 0.f, 0.f, 0.f};
    for (int it = 0; it < 32; ++it) {
        int cur = it & 1;
        if (it + 1 < 32) {
            const unsigned short* ph = qbh + (size_t)(it + 1) * (16 * 64);
            const unsigned short* pl = qbl + (size_t)(it + 1) * (16 * 64);
            nb[cur ^ 1][0] = *(const bf16x8*)ph;
            nb[cur ^ 1][1] = *(const bf16x8*)(ph + 32);
            nb[cur ^ 1][2] = *(const bf16x8*)pl;
            nb[cur ^ 1][3] = *(const bf16x8*)(pl + 32);
        }
        f32x4 s = {0.f, 0.f, 0.f, 0.f};
        s = MFMA16(ah0, nb[cur][0], s, 0, 0, 0);
        s = MFMA16(ah1, nb[cur][1], s, 0, 0, 0);
        s = MFMA16(ah0, nb[cur][2], s, 0, 0, 0);
        s = MFMA16(ah1, nb[cur][3], s, 0, 0, 0);
        s = MFMA16(al0, nb[cur][0], s, 0, 0, 0);
        s = MFMA16(al1, nb[cur][1], s, 0, 0, 0);
        int n = j * 512 + it * 16 + t;
        ushort4 e4;
        #pragma unroll
        for (int r = 0; r < 4; ++r) {
            float p = __expf(s[r] - COFF);
            ssum[r] += p;
            ((unsigned short*)&e4)[r] = f2bf(p);
        }
        *(ushort4*)(Eb + (size_t)n * 64 + 16 * i + qd * 4) = e4;
    }

    #pragma unroll
    for (int r = 0; r < 4; ++r) {
        float v = ssum[r];
        v += __shfl_xor(v, 1, 16);
        v += __shfl_xor(v, 2, 16);
        v += __shfl_xor(v, 4, 16);
        v += __shfl_xor(v, 8, 16);
        if (t == 0) csbuf[j][16 * i + qd * 4 + r] = v;
    }
    __syncthreads();
    if (tid < 64) {
        float cstot = csbuf[0][tid] + csbuf[1][tid] + csbuf[2][tid] + csbuf[3][tid];
        float rc = 1.0f / cstot;
        rcs_s[tid] = rc;
        rcsb[(size_t)b * 2048 + m0 + tid] = f2bf(rc);
    }
    __syncthreads();
    // scale this block's vt tile [b][mt][256][64] by rcs[m]
    // tile = 256*64 = 16384 elems = 2048 bf16x8 chunks; 1024 threads x 2.
    {
        unsigned short* vtp = vt + ((size_t)b * 32 + mt) * (256 * 64);
        #pragma unroll
        for (int u = 0; u < 2; ++u) {
            int idx = tid + u * 1024;
            bf16x8 v8 = *(bf16x8*)(vtp + idx * 8);
            int colb = (idx & 7) * 8;
            #pragma unroll
            for (int e = 0; e < 8; ++e)
                v8[e] = (short)f2bf(bf2f((unsigned short)v8[e]) * rcs_s[colb + e]);
            *(bf16x8*)(vtp + idx * 8) = v8;
        }
    }
}

// ---------------- kernel 3: PV GEMM out = (E·v') / rs ---------------------
// grid (64 nt, 2 dh, 8 b) = 1024 blocks, 256 thr = 4 waves.
// Block tile 32n x 128d; wave w: d0 = dh*128 + 32w, tile 32n x 32d.
// Register double-buffered loads; barrier-free main loop.
__global__ __launch_bounds__(256, 3) void k_pv(
    const unsigned short* __restrict__ E, const unsigned short* __restrict__ rcsb,
    const unsigned short* __restrict__ vt, float* __restrict__ out)
{
    __shared__ float rsbuf[32];
    int tid = threadIdx.x;
    int w = tid >> 6, lane = tid & 63;
    int t = lane & 15, qd = lane >> 4;
    int b = blockIdx.z, dh = blockIdx.y, nt = blockIdx.x;
    int n0 = nt * 32;
    int d0 = dh * 128 + w * 32;
    const bf16x8 zero8 = {0, 0, 0, 0, 0, 0, 0, 0};

    const unsigned short* Ebase = E + ((size_t)b * 32) * (2048 * 64) + (size_t)(n0 + t) * 64 + qd * 8;
    const unsigned short* Vbase = vt + ((size_t)b * 32) * (256 * 64) + (size_t)(d0 + t) * 64 + qd * 8;
    const unsigned short* Rbase = rcsb + (size_t)b * 2048 + qd * 8;

    bf16x8 AE[2][2][2], BV[2][2][2], BR[2][2];

#define LOADF(buf, mtv) do { \
        const unsigned short* ep = Ebase + (size_t)(mtv) * (2048 * 64); \
        AE[buf][0][0] = *(const bf16x8*)ep; \
        AE[buf][0][1] = *(const bf16x8*)(ep + 32); \
        AE[buf][1][0] = *(const bf16x8*)(ep + 16 * 64); \
        AE[buf][1][1] = *(const bf16x8*)(ep + 16 * 64 + 32); \
        const unsigned short* vp = Vbase + (size_t)(mtv) * (256 * 64); \
        BV[buf][0][0] = *(const bf16x8*)vp; \
        BV[buf][0][1] = *(const bf16x8*)(vp + 32); \
        BV[buf][1][0] = *(const bf16x8*)(vp + 16 * 64); \
        BV[buf][1][1] = *(const bf16x8*)(vp + 16 * 64 + 32); \
        const unsigned short* rp = Rbase + (mtv) * 64; \
        BR[buf][0] = (t == 0) ? *(const bf16x8*)rp : zero8; \
        BR[buf][1] = (t == 0) ? *(const bf16x8*)(rp + 32) : zero8; \
    } while (0)

    f32x4 acc[2][2], ars[2];
    #pragma unroll
    for (int g = 0; g < 2; ++g) {
        ars[g] = (f32x4){0.f, 0.f, 0.f, 0.f};
        #pragma unroll
        for (int c = 0; c < 2; ++c) acc[g][c] = (f32x4){0.f, 0.f, 0.f, 0.f};
    }

    LOADF(0, 0);
    for (int mt = 0; mt < 32; ++mt) {
        int cur = mt & 1;
        if (mt + 1 < 32) LOADF(cur ^ 1, mt + 1);
        #pragma unroll
        for (int g = 0; g < 2; ++g) {
            #pragma unroll
            for (int c = 0; c < 2; ++c) {
                acc[g][c] = MFMA16(AE[cur][g][0], BV[cur][c][0], acc[g][c], 0, 0, 0);
                acc[g][c] = MFMA16(AE[cur][g][1], BV[cur][c][1], acc[g][c], 0, 0, 0);
            }
            ars[g] = MFMA16(AE[cur][g][0], BR[cur][0], ars[g], 0, 0, 0);
            ars[g] = MFMA16(AE[cur][g][1], BR[cur][1], ars[g], 0, 0, 0);
        }
    }
#undef LOADF

    if (w == 0 && t == 0) {
        #pragma unroll
        for (int g = 0; g < 2; ++g)
            #pragma unroll
            for (int r = 0; r < 4; ++r) rsbuf[g * 16 + qd * 4 + r] = ars[g][r];
    }
    __syncthreads();

    #pragma unroll
    for (int g = 0; g < 2; ++g)
        #pragma unroll
        for (int r = 0; r < 4; ++r) {
            int nl = g * 16 + qd * 4 + r;
            float sc = 1.0f / (1e-9f + rsbuf[nl]);
            size_t orow = ((size_t)b * 2048 + n0 + nl) * 256;
            #pragma unroll
            for (int c = 0; c < 2; ++c)
                out[orow + d0 + c * 16 + t] = acc[g][c][r] * sc;
        }
}

extern "C" void kernel_launch(void* const* d_in, const int* in_sizes, int n_in,
                              void* d_out, int out_size, void* d_ws, size_t ws_size,
                              hipStream_t stream) {
    (void)in_sizes; (void)n_in; (void)out_size; (void)ws_size;
    const float* x  = (const float*)d_in[0];
    const float* Wq = (const float*)d_in[1];
    const float* Wk = (const float*)d_in[2];
    const float* Wv = (const float*)d_in[3];
    float* out = (float*)d_out;

    char* ws = (char*)d_ws;
    size_t off = 0;
    unsigned short* Wh = (unsigned short*)(ws + off); off += (size_t)384 * 256 * 2;
    unsigned short* Wl = (unsigned short*)(ws + off); off += (size_t)384 * 256 * 2;
    unsigned short* xh = (unsigned short*)(ws + off); off += (size_t)BB * NN * CC * 2;
    unsigned short* xl = (unsigned short*)(ws + off); off += (size_t)BB * NN * CC * 2;
    unsigned short* qh = (unsigned short*)(ws + off); off += (size_t)BB * NN * DKK * 2;
    unsigned short* ql = (unsigned short*)(ws + off); off += (size_t)BB * NN * DKK * 2;
    unsigned short* kh = (unsigned short*)(ws + off); off += (size_t)BB * NN * DKK * 2;
    unsigned short* kl = (unsigned short*)(ws + off); off += (size_t)BB * NN * DKK * 2;
    unsigned short* vt = (unsigned short*)(ws + off); off += (size_t)BB * DVV * NN * 2;
    unsigned short* rcsb = (unsigned short*)(ws + off); off += (size_t)BB * NN * 2;
    unsigned short* E  = (unsigned short*)(ws + off); off += (size_t)BB * NN * NN * 2;

    hipLaunchKernelGGL(k_wt,     dim3(384),         dim3(256),  0, stream, Wq, Wk, Wv, Wh, Wl);
    hipLaunchKernelGGL(k_split,  dim3(2048),        dim3(256),  0, stream, x, xh, xl);
    hipLaunchKernelGGL(k_vproj,  dim3(1024),        dim3(256),  0, stream, xh, Wh, vt);
    hipLaunchKernelGGL(k_qkproj, dim3(1024),        dim3(256),  0, stream, xh, xl, Wh, Wl, qh, ql, kh, kl);
    hipLaunchKernelGGL(k_qk,     dim3(NN / 64, BB), dim3(1024), 0, stream, qh, ql, kh, kl, E, rcsb, vt);
    hipLaunchKernelGGL(k_pv,     dim3(64, 2, BB),   dim3(256),  0, stream, E, rcsb, vt, out);
}

// Round 7
// 227.538 us; speedup vs baseline: 16.6524x; 16.6524x over previous
//
#include <hip/hip_runtime.h>
#include <hip/hip_bf16.h>

#define BB 8
#define NN 2048
#define CC 256
#define DKK 64
#define DVV 256
#define COFF 60.0f

typedef __attribute__((ext_vector_type(8))) short bf16x8;
typedef __attribute__((ext_vector_type(4))) float f32x4;

#define MFMA16 __builtin_amdgcn_mfma_f32_16x16x32_bf16

static __device__ __forceinline__ unsigned short f2bf(float f) {
    unsigned int u = __float_as_uint(f);
    u += 0x7fffu + ((u >> 16) & 1u);
    return (unsigned short)(u >> 16);
}
static __device__ __forceinline__ float bf2f(unsigned short h) {
    return __uint_as_float(((unsigned int)h) << 16);
}

// async global->LDS, 16B per lane; LDS dest = base + lane*16
static __device__ __forceinline__ void g2l16(const unsigned short* g, unsigned short* l) {
    __builtin_amdgcn_global_load_lds(
        (const __attribute__((address_space(1))) void*)g,
        (__attribute__((address_space(3))) void*)l, 16, 0, 0);
}

// ---------------- kernel 0: split W into bf16 h/l, rows: q(0..63)|k|v -----
__global__ void k_wt(const float* __restrict__ Wq, const float* __restrict__ Wk,
                     const float* __restrict__ Wv,
                     unsigned short* __restrict__ Wh, unsigned short* __restrict__ Wl) {
    int idx = blockIdx.x * 256 + threadIdx.x;
    if (idx >= 384 * 256) return;
    int d = idx >> 8, c = idx & 255;
    float w;
    if (d < 64)       w = Wq[d * 256 + c];
    else if (d < 128) w = Wk[(d - 64) * 256 + c];
    else              w = Wv[(d - 128) * 256 + c];
    unsigned short h = f2bf(w);
    Wh[idx] = h;
    Wl[idx] = f2bf(w - bf2f(h));
}

// ---------------- kernel 0b: split x into bf16 h/l ------------------------
__global__ __launch_bounds__(256) void k_split(
    const float* __restrict__ x,
    unsigned short* __restrict__ xh, unsigned short* __restrict__ xl) {
    int tid = blockIdx.x * 256 + threadIdx.x;
    const float4* xp = (const float4*)x + tid * 2;
    float4 a = xp[0], b = xp[1];
    float v[8] = {a.x, a.y, a.z, a.w, b.x, b.y, b.z, b.w};
    ushort4 h4[2], l4[2];
    #pragma unroll
    for (int i = 0; i < 8; ++i) {
        unsigned short h = f2bf(v[i]);
        ((unsigned short*)h4)[i] = h;
        ((unsigned short*)l4)[i] = f2bf(v[i] - bf2f(h));
    }
    ((ushort4*)xh)[tid * 2]     = h4[0];
    ((ushort4*)xh)[tid * 2 + 1] = h4[1];
    ((ushort4*)xl)[tid * 2]     = l4[0];
    ((ushort4*)xl)[tid * 2 + 1] = l4[1];
}

// ---------------- kernel 1a: v projection -> swizzled vT[b][d][2048] ------
// nsw swizzle per 64-m window so k_attn's global_load_lds image is plain.
__global__ __launch_bounds__(256) void k_vproj(
    const unsigned short* __restrict__ xh, const unsigned short* __restrict__ Wh,
    unsigned short* __restrict__ vT)
{
    int w = threadIdx.x >> 6, lane = threadIdx.x & 63;
    int t = lane & 15, qd = lane >> 4;
    int n0 = blockIdx.x * 16;
    int bn = n0 + t;
    bf16x8 bfr[8];
    const unsigned short* bp = xh + (size_t)bn * 256 + qd * 8;
    #pragma unroll
    for (int c = 0; c < 8; ++c) bfr[c] = *(const bf16x8*)(bp + c * 32);
    int b = bn >> 11, n = bn & 2047;
    #pragma unroll
    for (int k = 0; k < 4; ++k) {
        int dt = 8 + w * 4 + k;
        const unsigned short* ap = Wh + (size_t)(dt * 16 + t) * 256 + qd * 8;
        f32x4 acc = {0.f, 0.f, 0.f, 0.f};
        #pragma unroll
        for (int c = 0; c < 8; ++c) {
            bf16x8 a = *(const bf16x8*)(ap + c * 32);
            acc = MFMA16(a, bfr[c], acc, 0, 0, 0);
        }
        #pragma unroll
        for (int r = 0; r < 4; ++r) {
            int dvd = dt * 16 + qd * 4 + r - 128;
            int nsw = (n & ~63) | ((((n >> 3) ^ dvd) & 7) << 3) | (n & 7);
            vT[((size_t)b * 256 + dvd) * 2048 + nsw] = f2bf(acc[r]);
        }
    }
}

// ---------------- kernel 1b: q/k projection (3-pass split-bf16 MFMA) ------
// q plain; kh/kl rows XOR-swizzled per 8-chunk by (row&7) for colsum/attn.
__global__ __launch_bounds__(256) void k_qkproj(
    const unsigned short* __restrict__ xh, const unsigned short* __restrict__ xl,
    const unsigned short* __restrict__ Wh, const unsigned short* __restrict__ Wl,
    unsigned short* __restrict__ qh, unsigned short* __restrict__ ql,
    unsigned short* __restrict__ kh, unsigned short* __restrict__ kl)
{
    int w = threadIdx.x >> 6, lane = threadIdx.x & 63;
    int t = lane & 15, qd = lane >> 4;
    int n0 = blockIdx.x * 16;
    int bn = n0 + t;
    bf16x8 bh[8], bl[8];
    const unsigned short* bph = xh + (size_t)bn * 256 + qd * 8;
    const unsigned short* bpl = xl + (size_t)bn * 256 + qd * 8;
    #pragma unroll
    for (int c = 0; c < 8; ++c) {
        bh[c] = *(const bf16x8*)(bph + c * 32);
        bl[c] = *(const bf16x8*)(bpl + c * 32);
    }
    #pragma unroll
    for (int k = 0; k < 2; ++k) {
        int dt = w * 2 + k;
        const unsigned short* aph = Wh + (size_t)(dt * 16 + t) * 256 + qd * 8;
        const unsigned short* apl = Wl + (size_t)(dt * 16 + t) * 256 + qd * 8;
        f32x4 acc = {0.f, 0.f, 0.f, 0.f};
        #pragma unroll
        for (int c = 0; c < 8; ++c) {
            bf16x8 a = *(const bf16x8*)(aph + c * 32);
            bf16x8 al = *(const bf16x8*)(apl + c * 32);
            acc = MFMA16(a, bh[c], acc, 0, 0, 0);
            acc = MFMA16(a, bl[c], acc, 0, 0, 0);
            acc = MFMA16(al, bh[c], acc, 0, 0, 0);
        }
        ushort4 h4, l4;
        #pragma unroll
        for (int r = 0; r < 4; ++r) {
            unsigned short h = f2bf(acc[r]);
            ((unsigned short*)&h4)[r] = h;
            ((unsigned short*)&l4)[r] = f2bf(acc[r] - bf2f(h));
        }
        int dbase = dt * 16 + qd * 4;
        if (dbase < 64) {
            *(ushort4*)(qh + (size_t)bn * 64 + dbase) = h4;
            *(ushort4*)(ql + (size_t)bn * 64 + dbase) = l4;
        } else {
            int dd0 = dbase - 64;   // multiple of 4; stays within an 8-chunk
            int sw = ((((dd0 >> 3) ^ bn) & 7) << 3) | (dd0 & 7);
            *(ushort4*)(kh + (size_t)bn * 64 + sw) = h4;
            *(ushort4*)(kl + (size_t)bn * 64 + sw) = l4;
        }
    }
}

// ---------------- kernel 2: column sums cs[m] = sum_n exp(S[n,m]-60) -------
// 16 waves: wave = (i = m-subtile 0..3, j = n-quarter 0..3). grid (32,8).
__global__ __launch_bounds__(1024) void k_colsum(
    const unsigned short* __restrict__ qh, const unsigned short* __restrict__ ql,
    const unsigned short* __restrict__ kh, const unsigned short* __restrict__ kl,
    float* __restrict__ cs)
{
    __shared__ float csbuf[4][64];
    int tid = threadIdx.x;
    int w = tid >> 6, lane = tid & 63;
    int t = lane & 15, qd = lane >> 4;
    int b = blockIdx.y, m0 = blockIdx.x * 64;
    int i = w >> 2, j = w & 3;

    int arow = m0 + i * 16 + t;
    int off0 = ((qd ^ (arow & 7)) << 3);            // de-swizzle k-chunk
    const unsigned short* kbh = kh + ((size_t)b * 2048 + arow) * 64;
    const unsigned short* kbl = kl + ((size_t)b * 2048 + arow) * 64;
    bf16x8 ah0 = *(const bf16x8*)(kbh + off0);
    bf16x8 ah1 = *(const bf16x8*)(kbh + (off0 ^ 32));
    bf16x8 al0 = *(const bf16x8*)(kbl + off0);
    bf16x8 al1 = *(const bf16x8*)(kbl + (off0 ^ 32));

    float ssum[4] = {0.f, 0.f, 0.f, 0.f};
    for (int itn = 0; itn < 32; ++itn) {
        int brow = j * 512 + itn * 16 + t;
        const unsigned short* qbh = qh + ((size_t)b * 2048 + brow) * 64 + qd * 8;
        const unsigned short* qbl = ql + ((size_t)b * 2048 + brow) * 64 + qd * 8;
        bf16x8 bh0 = *(const bf16x8*)qbh;
        bf16x8 bh1 = *(const bf16x8*)(qbh + 32);
        bf16x8 bl0 = *(const bf16x8*)qbl;
        bf16x8 bl1 = *(const bf16x8*)(qbl + 32);
        f32x4 a0 = {0.f,0.f,0.f,0.f}, a1 = {0.f,0.f,0.f,0.f};
        a0 = MFMA16(ah0, bh0, a0, 0, 0, 0);
        a0 = MFMA16(ah1, bh1, a0, 0, 0, 0);
        a1 = MFMA16(ah0, bl0, a1, 0, 0, 0);
        a1 = MFMA16(ah1, bl1, a1, 0, 0, 0);
        a1 = MFMA16(al0, bh0, a1, 0, 0, 0);
        a1 = MFMA16(al1, bh1, a1, 0, 0, 0);
        #pragma unroll
        for (int r = 0; r < 4; ++r)
            ssum[r] += __expf((a0[r] + a1[r]) - COFF);
    }
    #pragma unroll
    for (int r = 0; r < 4; ++r) {
        float v = ssum[r];
        v += __shfl_xor(v, 1, 16);
        v += __shfl_xor(v, 2, 16);
        v += __shfl_xor(v, 4, 16);
        v += __shfl_xor(v, 8, 16);
        ssum[r] = v;
    }
    if (t == 0) {
        #pragma unroll
        for (int r = 0; r < 4; ++r) csbuf[j][i * 16 + qd * 4 + r] = ssum[r];
    }
    __syncthreads();
    if (tid < 64)
        cs[(size_t)b * 2048 + m0 + tid] =
            csbuf[0][tid] + csbuf[1][tid] + csbuf[2][tid] + csbuf[3][tid];
}

// ---------------- kernel 3: flash pass. 16 waves/block, grid (32,8). -------
__global__ __launch_bounds__(1024) void k_attn(
    const unsigned short* __restrict__ qh, const unsigned short* __restrict__ ql,
    const unsigned short* __restrict__ kh, const unsigned short* __restrict__ kl,
    const unsigned short* __restrict__ vT, const float* __restrict__ cs,
    float* __restrict__ out)
{
    __shared__ __align__(16) unsigned short kbuf[2][128 * 64];
    __shared__ __align__(16) unsigned short vbuf[2][256 * 64];
    __shared__ __align__(16) unsigned short pP[64 * 72];
    __shared__ float cs_s[2048];
    __shared__ float rsbuf[4][64];

    int tid = threadIdx.x;
    int w = tid >> 6, lane = tid & 63;
    int t = lane & 15, qd = lane >> 4;
    int b = blockIdx.y;
    int n0 = blockIdx.x * 64;
    int i = w >> 2, j = w & 3;
    int i2 = w >> 3, j8 = w & 7;

    for (int u = tid; u < 2048; u += 1024) cs_s[u] = cs[(size_t)b * 2048 + u];

    const unsigned short* qbh = qh + ((size_t)b * 2048 + n0 + i * 16 + t) * 64 + qd * 8;
    const unsigned short* qbl = ql + ((size_t)b * 2048 + n0 + i * 16 + t) * 64 + qd * 8;
    bf16x8 ah0 = *(const bf16x8*)qbh;
    bf16x8 ah1 = *(const bf16x8*)(qbh + 32);
    bf16x8 al0 = *(const bf16x8*)qbl;
    bf16x8 al1 = *(const bf16x8*)(qbl + 32);

    int lr = lane >> 3, lc = (lane & 7) << 3;
    const unsigned short* vsrc0 = vT + ((size_t)b * 256 + w * 16 + lr) * 2048 + lc;
    const unsigned short* vsrc1 = vT + ((size_t)b * 256 + w * 16 + 8 + lr) * 2048 + lc;
    const unsigned short* karr = (w < 8) ? kh : kl;
    const unsigned short* ksrc = karr + ((size_t)b * 2048 + (w & 7) * 8 + lr) * 64 + lc;
    unsigned short* vdst0 = &vbuf[0][0] + w * 1024;
    unsigned short* vdst1 = vdst0 + 512;
    unsigned short* kdst = &kbuf[0][0] + w * 512;

#define STAGE(bufi, m0s) do { \
        g2l16(vsrc0 + (m0s), vdst0 + (bufi) * 16384); \
        g2l16(vsrc1 + (m0s), vdst1 + (bufi) * 16384); \
        g2l16(ksrc + (size_t)(m0s) * 64, kdst + (bufi) * 8192); \
    } while (0)

    f32x4 accv[2][2];
    accv[0][0] = (f32x4){0.f,0.f,0.f,0.f}; accv[0][1] = (f32x4){0.f,0.f,0.f,0.f};
    accv[1][0] = (f32x4){0.f,0.f,0.f,0.f}; accv[1][1] = (f32x4){0.f,0.f,0.f,0.f};
    float rs[4] = {0.f, 0.f, 0.f, 0.f};

    STAGE(0, 0);

    for (int it = 0; it < 32; ++it) {
        __syncthreads();
        int cur = it & 1;
        int m0 = it * 64;
        {
            int mr = j * 16 + t;
            int off0 = ((qd ^ (t & 7)) << 3);
            const unsigned short* khrow = &kbuf[cur][mr * 64];
            const unsigned short* klrow = &kbuf[cur][(64 + mr) * 64];
            bf16x8 bh0 = *(const bf16x8*)(khrow + off0);
            bf16x8 bh1 = *(const bf16x8*)(khrow + (off0 ^ 32));
            bf16x8 bl0 = *(const bf16x8*)(klrow + off0);
            bf16x8 bl1 = *(const bf16x8*)(klrow + (off0 ^ 32));
            f32x4 s0 = {0.f,0.f,0.f,0.f}, s1 = {0.f,0.f,0.f,0.f};
            s0 = MFMA16(ah0, bh0, s0, 0, 0, 0);
            s0 = MFMA16(ah1, bh1, s0, 0, 0, 0);
            s1 = MFMA16(ah0, bl0, s1, 0, 0, 0);
            s1 = MFMA16(ah1, bl1, s1, 0, 0, 0);
            s1 = MFMA16(al0, bh0, s1, 0, 0, 0);
            s1 = MFMA16(al1, bh1, s1, 0, 0, 0);
            float rcs = 1.0f / cs_s[m0 + j * 16 + t];
            unsigned short* prow = pP + (size_t)(i * 16 + qd * 4) * 72 + j * 16 + t;
            #pragma unroll
            for (int r = 0; r < 4; ++r) {
                float p = __expf((s0[r] + s1[r]) - COFF) * rcs;
                rs[r] += p;
                prow[r * 72] = f2bf(p);
            }
        }
        if (it + 1 < 32) STAGE((it + 1) & 1, m0 + 64);
        __syncthreads();
        {
            const unsigned short* vb = &vbuf[cur][0];
            #pragma unroll
            for (int c = 0; c < 2; ++c) {
                bf16x8 pa0 = *(const bf16x8*)(pP + (size_t)((2*i2 + 0) * 16 + t) * 72 + c * 32 + qd * 8);
                bf16x8 pa1 = *(const bf16x8*)(pP + (size_t)((2*i2 + 1) * 16 + t) * 72 + c * 32 + qd * 8);
                int ch = (((c * 4 + qd) ^ (t & 7)) << 3);
                bf16x8 vb0 = *(const bf16x8*)(vb + ((2*j8 + 0) * 16 + t) * 64 + ch);
                bf16x8 vb1 = *(const bf16x8*)(vb + ((2*j8 + 1) * 16 + t) * 64 + ch);
                accv[0][0] = MFMA16(pa0, vb0, accv[0][0], 0, 0, 0);
                accv[0][1] = MFMA16(pa0, vb1, accv[0][1], 0, 0, 0);
                accv[1][0] = MFMA16(pa1, vb0, accv[1][0], 0, 0, 0);
                accv[1][1] = MFMA16(pa1, vb1, accv[1][1], 0, 0, 0);
            }
        }
    }
#undef STAGE

    #pragma unroll
    for (int r = 0; r < 4; ++r) {
        float v = rs[r];
        v += __shfl_xor(v, 1, 16);
        v += __shfl_xor(v, 2, 16);
        v += __shfl_xor(v, 4, 16);
        v += __shfl_xor(v, 8, 16);
        rs[r] = v;
    }
    if (t == 0) {
        #pragma unroll
        for (int r = 0; r < 4; ++r) rsbuf[j][i * 16 + qd * 4 + r] = rs[r];
    }
    __syncthreads();

    #pragma unroll
    for (int s2 = 0; s2 < 2; ++s2) {
        #pragma unroll
        for (int r = 0; r < 4; ++r) {
            int nl = (2 * i2 + s2) * 16 + qd * 4 + r;
            float tot = rsbuf[0][nl] + rsbuf[1][nl] + rsbuf[2][nl] + rsbuf[3][nl];
            float sc = 1.0f / (1e-9f + tot);
            size_t orow = ((size_t)b * 2048 + n0 + nl) * 256;
            out[orow + (2 * j8 + 0) * 16 + t] = accv[s2][0][r] * sc;
            out[orow + (2 * j8 + 1) * 16 + t] = accv[s2][1][r] * sc;
        }
    }
}

extern "C" void kernel_launch(void* const* d_in, const int* in_sizes, int n_in,
                              void* d_out, int out_size, void* d_ws, size_t ws_size,
                              hipStream_t stream) {
    (void)in_sizes; (void)n_in; (void)out_size; (void)ws_size;
    const float* x  = (const float*)d_in[0];
    const float* Wq = (const float*)d_in[1];
    const float* Wk = (const float*)d_in[2];
    const float* Wv = (const float*)d_in[3];
    float* out = (float*)d_out;

    char* ws = (char*)d_ws;
    size_t off = 0;
    unsigned short* Wh = (unsigned short*)(ws + off); off += (size_t)384 * 256 * 2;
    unsigned short* Wl = (unsigned short*)(ws + off); off += (size_t)384 * 256 * 2;
    unsigned short* xh = (unsigned short*)(ws + off); off += (size_t)BB * NN * CC * 2;
    unsigned short* xl = (unsigned short*)(ws + off); off += (size_t)BB * NN * CC * 2;
    unsigned short* qh = (unsigned short*)(ws + off); off += (size_t)BB * NN * DKK * 2;
    unsigned short* ql = (unsigned short*)(ws + off); off += (size_t)BB * NN * DKK * 2;
    unsigned short* kh = (unsigned short*)(ws + off); off += (size_t)BB * NN * DKK * 2;
    unsigned short* kl = (unsigned short*)(ws + off); off += (size_t)BB * NN * DKK * 2;
    unsigned short* vT = (unsigned short*)(ws + off); off += (size_t)BB * DVV * NN * 2;
    float* cs = (float*)(ws + off);                   off += (size_t)BB * NN * 4;

    hipLaunchKernelGGL(k_wt,     dim3(384),         dim3(256),  0, stream, Wq, Wk, Wv, Wh, Wl);
    hipLaunchKernelGGL(k_split,  dim3(2048),        dim3(256),  0, stream, x, xh, xl);
    hipLaunchKernelGGL(k_vproj,  dim3(1024),        dim3(256),  0, stream, xh, Wh, vT);
    hipLaunchKernelGGL(k_qkproj, dim3(1024),        dim3(256),  0, stream, xh, xl, Wh, Wl, qh, ql, kh, kl);
    hipLaunchKernelGGL(k_colsum, dim3(NN / 64, BB), dim3(1024), 0, stream, qh, ql, kh, kl, cs);
    hipLaunchKernelGGL(k_attn,   dim3(NN / 64, BB), dim3(1024), 0, stream, qh, ql, kh, kl, vT, cs, out);
}

// Round 8
// 167.481 us; speedup vs baseline: 22.6239x; 1.3586x over previous
//
#include <hip/hip_runtime.h>
#include <hip/hip_bf16.h>

#define BB 8
#define NN 2048
#define CC 256
#define DKK 64
#define DVV 256
#define COFF 60.0f

typedef __attribute__((ext_vector_type(8))) short bf16x8;
typedef __attribute__((ext_vector_type(4))) float f32x4;

#define MFMA16 __builtin_amdgcn_mfma_f32_16x16x32_bf16

static __device__ __forceinline__ unsigned short f2bf(float f) {
    unsigned int u = __float_as_uint(f);
    u += 0x7fffu + ((u >> 16) & 1u);
    return (unsigned short)(u >> 16);
}
static __device__ __forceinline__ float bf2f(unsigned short h) {
    return __uint_as_float(((unsigned int)h) << 16);
}

// async global->LDS, 16B per lane; LDS dest = wave-uniform base + lane*16
static __device__ __forceinline__ void g2l16(const unsigned short* g, unsigned short* l) {
    __builtin_amdgcn_global_load_lds(
        (const __attribute__((address_space(1))) void*)g,
        (__attribute__((address_space(3))) void*)l, 16, 0, 0);
}

// ---------------- kernel 0: split W -> swizzled bf16 images ---------------
// Wqk rows 0..63 = q, 64..127 = k (h and l planes); Wv rows 0..255 (h only).
// 256-elem rows, chunk c8=c>>3 stored at ((c8&24)|((c8^row)&7)).
__global__ void k_wt(const float* __restrict__ Wq, const float* __restrict__ Wk,
                     const float* __restrict__ Wv,
                     unsigned short* __restrict__ Wqkh_s, unsigned short* __restrict__ Wqkl_s,
                     unsigned short* __restrict__ Wvs) {
    int idx = blockIdx.x * 256 + threadIdx.x;
    if (idx >= 384 * 256) return;
    int d = idx >> 8, c = idx & 255;
    float w;
    if (d < 64)       w = Wq[d * 256 + c];
    else if (d < 128) w = Wk[(d - 64) * 256 + c];
    else              w = Wv[(d - 128) * 256 + c];
    unsigned short h = f2bf(w);
    int c8 = c >> 3;
    if (d < 128) {
        int row = d;
        int csw = (((c8 & 24) | ((c8 ^ row) & 7)) << 3) | (c & 7);
        Wqkh_s[row * 256 + csw] = h;
        Wqkl_s[row * 256 + csw] = f2bf(w - bf2f(h));
    } else {
        int row = d - 128;
        int csw = (((c8 & 24) | ((c8 ^ row) & 7)) << 3) | (c & 7);
        Wvs[row * 256 + csw] = h;
    }
}

// ---------------- kernel 0b: split x into bf16 h/l ------------------------
__global__ __launch_bounds__(256) void k_split(
    const float* __restrict__ x,
    unsigned short* __restrict__ xh, unsigned short* __restrict__ xl) {
    int tid = blockIdx.x * 256 + threadIdx.x;
    const float4* xp = (const float4*)x + tid * 2;
    float4 a = xp[0], b = xp[1];
    float v[8] = {a.x, a.y, a.z, a.w, b.x, b.y, b.z, b.w};
    ushort4 h4[2], l4[2];
    #pragma unroll
    for (int i = 0; i < 8; ++i) {
        unsigned short h = f2bf(v[i]);
        ((unsigned short*)h4)[i] = h;
        ((unsigned short*)l4)[i] = f2bf(v[i] - bf2f(h));
    }
    ((ushort4*)xh)[tid * 2]     = h4[0];
    ((ushort4*)xh)[tid * 2 + 1] = h4[1];
    ((ushort4*)xl)[tid * 2]     = l4[0];
    ((ushort4*)xl)[tid * 2 + 1] = l4[1];
}

// ---------------- kernel 1a: v projection, W staged in LDS ----------------
// grid 256 blocks (64 n-rows each), 16 waves: wave (i = n-sub, j = d-64-group).
__global__ __launch_bounds__(1024) void k_vproj(
    const unsigned short* __restrict__ xh, const unsigned short* __restrict__ Wvs,
    unsigned short* __restrict__ vT)
{
    __shared__ __align__(16) unsigned short Wlds[256 * 256];  // 128 KB
    int tid = threadIdx.x;
    int w = tid >> 6, lane = tid & 63;
    int t = lane & 15, qd = lane >> 4;
    int i = w >> 2, j = w & 3;
    int bn0 = blockIdx.x * 64;

    // one-time stage: 256 rows x 512B; 2 rows per wave-instr; 8 instrs/wave
    {
        int lr = lane >> 5, lc = (lane & 31) << 3;
        #pragma unroll
        for (int s = 0; s < 8; ++s) {
            int r0 = (w * 8 + s) * 2;
            g2l16(Wvs + (size_t)(r0 + lr) * 256 + lc, &Wlds[0] + (size_t)r0 * 256);
        }
    }

    int bn = bn0 + i * 16 + t;
    int b = bn >> 11, n = bn & 2047;
    bf16x8 bfr[8];
    const unsigned short* bp = xh + (size_t)bn * 256 + qd * 8;
    #pragma unroll
    for (int c = 0; c < 8; ++c) bfr[c] = *(const bf16x8*)(bp + c * 32);

    __syncthreads();

    f32x4 acc[4];
    #pragma unroll
    for (int k = 0; k < 4; ++k) acc[k] = (f32x4){0.f, 0.f, 0.f, 0.f};
    #pragma unroll
    for (int c = 0; c < 8; ++c) {
        #pragma unroll
        for (int k = 0; k < 4; ++k) {
            int d = j * 64 + k * 16 + t;          // d&7 == t&7
            int c8 = c * 4 + qd;
            int pos = d * 256 + ((((c8 & 24) | ((c8 ^ t) & 7))) << 3);
            bf16x8 a = *(const bf16x8*)(&Wlds[pos]);
            acc[k] = MFMA16(a, bfr[c], acc[k], 0, 0, 0);
        }
    }
    #pragma unroll
    for (int k = 0; k < 4; ++k) {
        #pragma unroll
        for (int r = 0; r < 4; ++r) {
            int dvd = j * 64 + k * 16 + qd * 4 + r;
            int nsw = (n & ~63) | ((((n >> 3) ^ dvd) & 7) << 3) | (n & 7);
            vT[((size_t)b * 256 + dvd) * 2048 + nsw] = f2bf(acc[k][r]);
        }
    }
}

// ---------------- kernel 1b: q/k projection, W(h+l) staged in LDS ---------
// grid 256 blocks (64 n-rows), 16 waves: wave (i = n-sub, j = d-32-group).
// Outputs qh/ql/kh/kl all row-XOR chunk-swizzled.
__global__ __launch_bounds__(1024) void k_qkproj(
    const unsigned short* __restrict__ xh, const unsigned short* __restrict__ xl,
    const unsigned short* __restrict__ Wqkh_s, const unsigned short* __restrict__ Wqkl_s,
    unsigned short* __restrict__ qh, unsigned short* __restrict__ ql,
    unsigned short* __restrict__ kh, unsigned short* __restrict__ kl)
{
    __shared__ __align__(16) unsigned short Wlds[2][128 * 256];  // 128 KB: h, l
    int tid = threadIdx.x;
    int w = tid >> 6, lane = tid & 63;
    int t = lane & 15, qd = lane >> 4;
    int i = w >> 2, j = w & 3;
    int bn0 = blockIdx.x * 64;

    {
        int lr = lane >> 5, lc = (lane & 31) << 3;
        #pragma unroll
        for (int s = 0; s < 8; ++s) {
            int id = w * 8 + s;                 // 0..127
            int plane = id >> 6;
            int r0 = (id & 63) * 2;
            const unsigned short* src = (plane ? Wqkl_s : Wqkh_s) + (size_t)(r0 + lr) * 256 + lc;
            g2l16(src, &Wlds[plane][0] + (size_t)r0 * 256);
        }
    }

    int bn = bn0 + i * 16 + t;
    bf16x8 bh[8], bl[8];
    const unsigned short* bph = xh + (size_t)bn * 256 + qd * 8;
    const unsigned short* bpl = xl + (size_t)bn * 256 + qd * 8;
    #pragma unroll
    for (int c = 0; c < 8; ++c) {
        bh[c] = *(const bf16x8*)(bph + c * 32);
        bl[c] = *(const bf16x8*)(bpl + c * 32);
    }

    __syncthreads();

    f32x4 acc[2];
    acc[0] = (f32x4){0.f, 0.f, 0.f, 0.f};
    acc[1] = (f32x4){0.f, 0.f, 0.f, 0.f};
    #pragma unroll
    for (int c = 0; c < 8; ++c) {
        #pragma unroll
        for (int k = 0; k < 2; ++k) {
            int d = j * 32 + k * 16 + t;        // d&7 == t&7
            int c8 = c * 4 + qd;
            int pos = d * 256 + ((((c8 & 24) | ((c8 ^ t) & 7))) << 3);
            bf16x8 ah = *(const bf16x8*)(&Wlds[0][pos]);
            bf16x8 al = *(const bf16x8*)(&Wlds[1][pos]);
            acc[k] = MFMA16(ah, bh[c], acc[k], 0, 0, 0);
            acc[k] = MFMA16(ah, bl[c], acc[k], 0, 0, 0);
            acc[k] = MFMA16(al, bh[c], acc[k], 0, 0, 0);
        }
    }
    #pragma unroll
    for (int k = 0; k < 2; ++k) {
        ushort4 h4, l4;
        #pragma unroll
        for (int r = 0; r < 4; ++r) {
            unsigned short h = f2bf(acc[k][r]);
            ((unsigned short*)&h4)[r] = h;
            ((unsigned short*)&l4)[r] = f2bf(acc[k][r] - bf2f(h));
        }
        int dbase = j * 32 + k * 16 + qd * 4;   // 0..127
        int dd = dbase & 63;
        int sw = ((((dd >> 3) ^ bn) & 7) << 3) | (dd & 7);
        if (dbase < 64) {
            *(ushort4*)(qh + (size_t)bn * 64 + sw) = h4;
            *(ushort4*)(ql + (size_t)bn * 64 + sw) = l4;
        } else {
            *(ushort4*)(kh + (size_t)bn * 64 + sw) = h4;
            *(ushort4*)(kl + (size_t)bn * 64 + sw) = l4;
        }
    }
}

// ---------------- kernel 2: column sums, q-tile staged in LDS -------------
// grid (32 mt, 8 b), 16 waves: wave (i = m-sub, j = n-sub) of each 64x64 S-tile.
// 32 iterations over n; q h+l 64-row tile double-buffered via global_load_lds.
__global__ __launch_bounds__(1024) void k_colsum(
    const unsigned short* __restrict__ qh, const unsigned short* __restrict__ ql,
    const unsigned short* __restrict__ kh, const unsigned short* __restrict__ kl,
    float* __restrict__ cs)
{
    __shared__ __align__(16) unsigned short qbuf[2][2][64 * 64];  // [buf][h/l] 32 KB
    __shared__ float csbuf[4][64];
    int tid = threadIdx.x;
    int w = tid >> 6, lane = tid & 63;
    int t = lane & 15, qd = lane >> 4;
    int b = blockIdx.y, m0 = blockIdx.x * 64;
    int i = w >> 2, j = w & 3;

    // persistent k A-frags (deswizzled): rows m0 + 16i + t
    int arow = m0 + i * 16 + t;
    int off0 = ((qd ^ (t & 7)) << 3);          // arow&7 == t&7
    const unsigned short* kbh = kh + ((size_t)b * 2048 + arow) * 64;
    const unsigned short* kbl = kl + ((size_t)b * 2048 + arow) * 64;
    bf16x8 ah0 = *(const bf16x8*)(kbh + off0);
    bf16x8 ah1 = *(const bf16x8*)(kbh + (off0 ^ 32));
    bf16x8 al0 = *(const bf16x8*)(kbl + off0);
    bf16x8 al1 = *(const bf16x8*)(kbl + (off0 ^ 32));

    // staging: wave w: plane w>>3, rows (w&7)*8 .. +8 of each 64-row tile
    int lr = lane >> 3, lc = (lane & 7) << 3;
    const unsigned short* qsrc = ((w < 8) ? qh : ql) +
        ((size_t)b * 2048 + (w & 7) * 8 + lr) * 64 + lc;
    unsigned short* qdst = &qbuf[0][w >> 3][(w & 7) * 8 * 64];

#define STAGEQ(bufi, itv) g2l16(qsrc + (size_t)(itv) * (64 * 64), qdst + (bufi) * (2 * 64 * 64))

    float ssum[4] = {0.f, 0.f, 0.f, 0.f};
    STAGEQ(0, 0);
    for (int it = 0; it < 32; ++it) {
        __syncthreads();                        // tile `it` staged; buf^1 free
        if (it + 1 < 32) STAGEQ((it + 1) & 1, it + 1);
        int cur = it & 1;
        int brow = j * 16 + t;                  // brow&7 == t&7
        const unsigned short* qrh = &qbuf[cur][0][brow * 64];
        const unsigned short* qrl = &qbuf[cur][1][brow * 64];
        bf16x8 bh0 = *(const bf16x8*)(qrh + off0);
        bf16x8 bh1 = *(const bf16x8*)(qrh + (off0 ^ 32));
        bf16x8 bl0 = *(const bf16x8*)(qrl + off0);
        bf16x8 bl1 = *(const bf16x8*)(qrl + (off0 ^ 32));
        f32x4 a0 = {0.f,0.f,0.f,0.f}, a1 = {0.f,0.f,0.f,0.f};
        a0 = MFMA16(ah0, bh0, a0, 0, 0, 0);
        a0 = MFMA16(ah1, bh1, a0, 0, 0, 0);
        a1 = MFMA16(ah0, bl0, a1, 0, 0, 0);
        a1 = MFMA16(ah1, bl1, a1, 0, 0, 0);
        a1 = MFMA16(al0, bh0, a1, 0, 0, 0);
        a1 = MFMA16(al1, bh1, a1, 0, 0, 0);
        #pragma unroll
        for (int r = 0; r < 4; ++r)
            ssum[r] += __expf((a0[r] + a1[r]) - COFF);
    }
#undef STAGEQ

    #pragma unroll
    for (int r = 0; r < 4; ++r) {
        float v = ssum[r];
        v += __shfl_xor(v, 1, 16);
        v += __shfl_xor(v, 2, 16);
        v += __shfl_xor(v, 4, 16);
        v += __shfl_xor(v, 8, 16);
        ssum[r] = v;
    }
    if (t == 0) {
        #pragma unroll
        for (int r = 0; r < 4; ++r) csbuf[j][i * 16 + qd * 4 + r] = ssum[r];
    }
    __syncthreads();
    if (tid < 64)
        cs[(size_t)b * 2048 + m0 + tid] =
            csbuf[0][tid] + csbuf[1][tid] + csbuf[2][tid] + csbuf[3][tid];
}

// ---------------- kernel 3: flash pass. 16 waves/block, grid (32,8). -------
__global__ __launch_bounds__(1024) void k_attn(
    const unsigned short* __restrict__ qh, const unsigned short* __restrict__ ql,
    const unsigned short* __restrict__ kh, const unsigned short* __restrict__ kl,
    const unsigned short* __restrict__ vT, const float* __restrict__ cs,
    float* __restrict__ out)
{
    __shared__ __align__(16) unsigned short kbuf[2][128 * 64];
    __shared__ __align__(16) unsigned short vbuf[2][256 * 64];
    __shared__ __align__(16) unsigned short pP[64 * 72];
    __shared__ float cs_s[2048];
    __shared__ float rsbuf[4][64];

    int tid = threadIdx.x;
    int w = tid >> 6, lane = tid & 63;
    int t = lane & 15, qd = lane >> 4;
    int b = blockIdx.y;
    int n0 = blockIdx.x * 64;
    int i = w >> 2, j = w & 3;
    int i2 = w >> 3, j8 = w & 7;

    for (int u = tid; u < 2048; u += 1024) cs_s[u] = cs[(size_t)b * 2048 + u];

    // persistent q A-frags (qh/ql now swizzled -> deswizzle like k-frags)
    int arow_a = n0 + i * 16 + t;
    int offq = ((qd ^ (t & 7)) << 3);          // arow_a&7 == t&7
    const unsigned short* qbh = qh + ((size_t)b * 2048 + arow_a) * 64;
    const unsigned short* qbl = ql + ((size_t)b * 2048 + arow_a) * 64;
    bf16x8 ah0 = *(const bf16x8*)(qbh + offq);
    bf16x8 ah1 = *(const bf16x8*)(qbh + (offq ^ 32));
    bf16x8 al0 = *(const bf16x8*)(qbl + offq);
    bf16x8 al1 = *(const bf16x8*)(qbl + (offq ^ 32));

    int lr = lane >> 3, lc = (lane & 7) << 3;
    const unsigned short* vsrc0 = vT + ((size_t)b * 256 + w * 16 + lr) * 2048 + lc;
    const unsigned short* vsrc1 = vT + ((size_t)b * 256 + w * 16 + 8 + lr) * 2048 + lc;
    const unsigned short* karr = (w < 8) ? kh : kl;
    const unsigned short* ksrc = karr + ((size_t)b * 2048 + (w & 7) * 8 + lr) * 64 + lc;
    unsigned short* vdst0 = &vbuf[0][0] + w * 1024;
    unsigned short* vdst1 = vdst0 + 512;
    unsigned short* kdst = &kbuf[0][0] + w * 512;

#define STAGE(bufi, m0s) do { \
        g2l16(vsrc0 + (m0s), vdst0 + (bufi) * 16384); \
        g2l16(vsrc1 + (m0s), vdst1 + (bufi) * 16384); \
        g2l16(ksrc + (size_t)(m0s) * 64, kdst + (bufi) * 8192); \
    } while (0)

    f32x4 accv[2][2];
    accv[0][0] = (f32x4){0.f,0.f,0.f,0.f}; accv[0][1] = (f32x4){0.f,0.f,0.f,0.f};
    accv[1][0] = (f32x4){0.f,0.f,0.f,0.f}; accv[1][1] = (f32x4){0.f,0.f,0.f,0.f};
    float rs[4] = {0.f, 0.f, 0.f, 0.f};

    STAGE(0, 0);

    for (int it = 0; it < 32; ++it) {
        __syncthreads();
        int cur = it & 1;
        int m0 = it * 64;
        {
            int mr = j * 16 + t;
            int off0 = ((qd ^ (t & 7)) << 3);
            const unsigned short* khrow = &kbuf[cur][mr * 64];
            const unsigned short* klrow = &kbuf[cur][(64 + mr) * 64];
            bf16x8 bh0 = *(const bf16x8*)(khrow + off0);
            bf16x8 bh1 = *(const bf16x8*)(khrow + (off0 ^ 32));
            bf16x8 bl0 = *(const bf16x8*)(klrow + off0);
            bf16x8 bl1 = *(const bf16x8*)(klrow + (off0 ^ 32));
            f32x4 s0 = {0.f,0.f,0.f,0.f}, s1 = {0.f,0.f,0.f,0.f};
            s0 = MFMA16(ah0, bh0, s0, 0, 0, 0);
            s0 = MFMA16(ah1, bh1, s0, 0, 0, 0);
            s1 = MFMA16(ah0, bl0, s1, 0, 0, 0);
            s1 = MFMA16(ah1, bl1, s1, 0, 0, 0);
            s1 = MFMA16(al0, bh0, s1, 0, 0, 0);
            s1 = MFMA16(al1, bh1, s1, 0, 0, 0);
            float rcs = 1.0f / cs_s[m0 + j * 16 + t];
            unsigned short* prow = pP + (size_t)(i * 16 + qd * 4) * 72 + j * 16 + t;
            #pragma unroll
            for (int r = 0; r < 4; ++r) {
                float p = __expf((s0[r] + s1[r]) - COFF) * rcs;
                rs[r] += p;
                prow[r * 72] = f2bf(p);
            }
        }
        if (it + 1 < 32) STAGE((it + 1) & 1, m0 + 64);
        __syncthreads();
        {
            const unsigned short* vb = &vbuf[cur][0];
            #pragma unroll
            for (int c = 0; c < 2; ++c) {
                bf16x8 pa0 = *(const bf16x8*)(pP + (size_t)((2*i2 + 0) * 16 + t) * 72 + c * 32 + qd * 8);
                bf16x8 pa1 = *(const bf16x8*)(pP + (size_t)((2*i2 + 1) * 16 + t) * 72 + c * 32 + qd * 8);
                int ch = (((c * 4 + qd) ^ (t & 7)) << 3);
                bf16x8 vb0 = *(const bf16x8*)(vb + ((2*j8 + 0) * 16 + t) * 64 + ch);
                bf16x8 vb1 = *(const bf16x8*)(vb + ((2*j8 + 1) * 16 + t) * 64 + ch);
                accv[0][0] = MFMA16(pa0, vb0, accv[0][0], 0, 0, 0);
                accv[0][1] = MFMA16(pa0, vb1, accv[0][1], 0, 0, 0);
                accv[1][0] = MFMA16(pa1, vb0, accv[1][0], 0, 0, 0);
                accv[1][1] = MFMA16(pa1, vb1, accv[1][1], 0, 0, 0);
            }
        }
    }
#undef STAGE

    #pragma unroll
    for (int r = 0; r < 4; ++r) {
        float v = rs[r];
        v += __shfl_xor(v, 1, 16);
        v += __shfl_xor(v, 2, 16);
        v += __shfl_xor(v, 4, 16);
        v += __shfl_xor(v, 8, 16);
        rs[r] = v;
    }
    if (t == 0) {
        #pragma unroll
        for (int r = 0; r < 4; ++r) rsbuf[j][i * 16 + qd * 4 + r] = rs[r];
    }
    __syncthreads();

    #pragma unroll
    for (int s2 = 0; s2 < 2; ++s2) {
        #pragma unroll
        for (int r = 0; r < 4; ++r) {
            int nl = (2 * i2 + s2) * 16 + qd * 4 + r;
            float tot = rsbuf[0][nl] + rsbuf[1][nl] + rsbuf[2][nl] + rsbuf[3][nl];
            float sc = 1.0f / (1e-9f + tot);
            size_t orow = ((size_t)b * 2048 + n0 + nl) * 256;
            out[orow + (2 * j8 + 0) * 16 + t] = accv[s2][0][r] * sc;
            out[orow + (2 * j8 + 1) * 16 + t] = accv[s2][1][r] * sc;
        }
    }
}

extern "C" void kernel_launch(void* const* d_in, const int* in_sizes, int n_in,
                              void* d_out, int out_size, void* d_ws, size_t ws_size,
                              hipStream_t stream) {
    (void)in_sizes; (void)n_in; (void)out_size; (void)ws_size;
    const float* x  = (const float*)d_in[0];
    const float* Wq = (const float*)d_in[1];
    const float* Wk = (const float*)d_in[2];
    const float* Wv = (const float*)d_in[3];
    float* out = (float*)d_out;

    char* ws = (char*)d_ws;
    size_t off = 0;
    unsigned short* Wqkh_s = (unsigned short*)(ws + off); off += (size_t)128 * 256 * 2;
    unsigned short* Wqkl_s = (unsigned short*)(ws + off); off += (size_t)128 * 256 * 2;
    unsigned short* Wvs    = (unsigned short*)(ws + off); off += (size_t)256 * 256 * 2;
    unsigned short* xh = (unsigned short*)(ws + off); off += (size_t)BB * NN * CC * 2;
    unsigned short* xl = (unsigned short*)(ws + off); off += (size_t)BB * NN * CC * 2;
    unsigned short* qh = (unsigned short*)(ws + off); off += (size_t)BB * NN * DKK * 2;
    unsigned short* ql = (unsigned short*)(ws + off); off += (size_t)BB * NN * DKK * 2;
    unsigned short* kh = (unsigned short*)(ws + off); off += (size_t)BB * NN * DKK * 2;
    unsigned short* kl = (unsigned short*)(ws + off); off += (size_t)BB * NN * DKK * 2;
    unsigned short* vT = (unsigned short*)(ws + off); off += (size_t)BB * DVV * NN * 2;
    float* cs = (float*)(ws + off);                   off += (size_t)BB * NN * 4;

    hipLaunchKernelGGL(k_wt,     dim3(384),         dim3(256),  0, stream, Wq, Wk, Wv, Wqkh_s, Wqkl_s, Wvs);
    hipLaunchKernelGGL(k_split,  dim3(2048),        dim3(256),  0, stream, x, xh, xl);
    hipLaunchKernelGGL(k_vproj,  dim3(256),         dim3(1024), 0, stream, xh, Wvs, vT);
    hipLaunchKernelGGL(k_qkproj, dim3(256),         dim3(1024), 0, stream, xh, xl, Wqkh_s, Wqkl_s, qh, ql, kh, kl);
    hipLaunchKernelGGL(k_colsum, dim3(NN / 64, BB), dim3(1024), 0, stream, qh, ql, kh, kl, cs);
    hipLaunchKernelGGL(k_attn,   dim3(NN / 64, BB), dim3(1024), 0, stream, qh, ql, kh, kl, vT, cs, out);
}